// Round 1
// baseline (1936.995 us; speedup 1.0000x reference)
//
#include <hip/hip_runtime.h>
#include <hip/hip_bf16.h>
#include <cmath>

// ---------------------------------------------------------------------------
// IntegerDiscreteFlow on MI355X (gfx950)
// B=8192, D=1024, d2=512, N=2048, F=8 steps.
// State S (8192x1024 f32) updated in place; the [:, ::-1] reversal is an
// orientation bit (logical j <-> stored 1023-j), flipped each step.
// GEMMs in bf16 MFMA 16x16x32, fp32 accumulate, m97-style 128x128x32 tiles.
// ---------------------------------------------------------------------------

typedef __bf16 bf16_t;
typedef bf16_t bf16x8 __attribute__((ext_vector_type(8)));
typedef float floatx4 __attribute__((ext_vector_type(4)));

#define BQ 8192
#define DD 1024
#define D2 512
#define NH 2048
#define NF 8

__device__ __forceinline__ void gload_lds16(const void* g, void* l) {
    __builtin_amdgcn_global_load_lds(
        (__attribute__((address_space(1))) void*)g,
        (__attribute__((address_space(3))) void*)l, 16, 0, 0);
}

// ---- weight convert+transpose: W (K x N f32, row-major) -> Wt (N x K bf16) --
__global__ __launch_bounds__(256)
void transpose_bf16(const float* __restrict__ W, bf16_t* __restrict__ Wt,
                    int K, int N) {
    __shared__ float tile[32][33];
    size_t fo = (size_t)blockIdx.z * K * N;
    int n0 = blockIdx.x * 32, k0 = blockIdx.y * 32;
    int tx = threadIdx.x & 31, ty = threadIdx.x >> 5;   // 32 x 8
    for (int i = 0; i < 4; i++)
        tile[ty + i*8][tx] = W[fo + (size_t)(k0 + ty + i*8) * N + n0 + tx];
    __syncthreads();
    for (int i = 0; i < 4; i++)
        Wt[fo + (size_t)(n0 + ty + i*8) * K + k0 + tx] = (bf16_t)tile[tx][ty + i*8];
}

// ---- copy x -> S (f32, vectorized) ----
__global__ __launch_bounds__(256)
void copy_x(const float4* __restrict__ x, float4* __restrict__ S) {
    int idx = blockIdx.x * blockDim.x + threadIdx.x;   // 2M threads
    S[idx] = x[idx];
}

// ---- build bf16 A operand (= logical xa) from S under orientation r ----
__global__ __launch_bounds__(256)
void prep_A(const float* __restrict__ S, bf16_t* __restrict__ Ab, int rflag) {
    int idx = blockIdx.x * blockDim.x + threadIdx.x;   // over 8192*512
    int m = idx >> 9;
    int j = idx & 511;
    int src = rflag ? (1023 - j) : j;
    Ab[idx] = (bf16_t)S[(size_t)m * DD + src];
}

// ---- GEMM: C = A(MxK bf16) @ B, B given transposed as Bt (NxK bf16) ----
// MODE 0: out = bf16( leaky_relu(acc + bias[n]) )
// MODE 1: S[m, slot(n)] += rint(acc + bias[n])   (in-place flow update)
template<int MODE>
__global__ __launch_bounds__(256)
void gemm_kernel(const bf16_t* __restrict__ A, const bf16_t* __restrict__ Bt,
                 const float* __restrict__ bias,
                 bf16_t* __restrict__ Cout, float* __restrict__ S,
                 int N, int K, int rflag)
{
    __shared__ __align__(16) bf16_t As[128 * 32];
    __shared__ __align__(16) bf16_t Bs[128 * 32];

    const int tid  = threadIdx.x;
    const int lane = tid & 63;
    const int wave = tid >> 6;
    const int wm   = wave >> 1;            // 0..1
    const int wn   = wave & 1;             // 0..1
    const int m0   = blockIdx.y * 128;
    const int n0   = blockIdx.x * 128;

    // staging: 256 threads x 16B = 4KB per issue; each 8KB tile = 2 issues.
    const int srow = tid >> 2;             // 0..63
    const int scol = (tid & 3) * 8;        // bf16 elems within 32-elem row
    const bf16_t* ag0 = A  + (size_t)(m0 + srow)      * K + scol;
    const bf16_t* ag1 = A  + (size_t)(m0 + 64 + srow) * K + scol;
    const bf16_t* bg0 = Bt + (size_t)(n0 + srow)      * K + scol;
    const bf16_t* bg1 = Bt + (size_t)(n0 + 64 + srow) * K + scol;
    bf16_t* as0 = &As[tid * 8];
    bf16_t* as1 = &As[2048 + tid * 8];
    bf16_t* bs0 = &Bs[tid * 8];
    bf16_t* bs1 = &Bs[2048 + tid * 8];

    floatx4 acc[4][4];
#pragma unroll
    for (int i = 0; i < 4; i++)
#pragma unroll
        for (int j = 0; j < 4; j++)
            acc[i][j] = (floatx4){0.f, 0.f, 0.f, 0.f};

    const int fr = lane & 15;              // fragment row/col within 16
    const int fk = (lane >> 4) * 8;        // fragment k offset

    for (int k0 = 0; k0 < K; k0 += 32) {
        __syncthreads();
        gload_lds16(ag0, as0);
        gload_lds16(ag1, as1);
        gload_lds16(bg0, bs0);
        gload_lds16(bg1, bs1);
        ag0 += 32; ag1 += 32; bg0 += 32; bg1 += 32;
        __syncthreads();

        bf16x8 af[4], bff[4];
#pragma unroll
        for (int i = 0; i < 4; i++)
            af[i] = *(const bf16x8*)&As[(wm*64 + i*16 + fr) * 32 + fk];
#pragma unroll
        for (int j = 0; j < 4; j++)
            bff[j] = *(const bf16x8*)&Bs[(wn*64 + j*16 + fr) * 32 + fk];
#pragma unroll
        for (int i = 0; i < 4; i++)
#pragma unroll
            for (int j = 0; j < 4; j++)
                acc[i][j] = __builtin_amdgcn_mfma_f32_16x16x32_bf16(
                                af[i], bff[j], acc[i][j], 0, 0, 0);
    }

    // epilogue: C[row, col], col = lane&15, row = (lane>>4)*4 + r  (m89 layout)
    const int ccol  = lane & 15;
    const int crow4 = (lane >> 4) * 4;
#pragma unroll
    for (int j = 0; j < 4; j++) {
        int col = n0 + wn*64 + j*16 + ccol;
        float bj = bias[col];
        if (MODE == 0) {
#pragma unroll
            for (int i = 0; i < 4; i++) {
#pragma unroll
                for (int r = 0; r < 4; r++) {
                    int row = m0 + wm*64 + i*16 + crow4 + r;
                    float v = acc[i][j][r] + bj;
                    v = v >= 0.f ? v : 0.01f * v;
                    Cout[(size_t)row * N + col] = (bf16_t)v;
                }
            }
        } else {
            int slot = rflag ? (511 - col) : (512 + col);
#pragma unroll
            for (int i = 0; i < 4; i++) {
#pragma unroll
                for (int r = 0; r < 4; r++) {
                    int row = m0 + wm*64 + i*16 + crow4 + r;
                    float t = acc[i][j][r] + bj;
                    float* p = &S[(size_t)row * DD + slot];
                    *p = *p + rintf(t);
                }
            }
        }
    }
}

// ---- final discretized-logistic NLL reduction ----
__global__ __launch_bounds__(256)
void reduce_nll(const float* __restrict__ S, const float* __restrict__ mean,
                const float* __restrict__ log_scale, float* __restrict__ out)
{
    float local = 0.f;
    const int total = BQ * DD;
    for (int idx = blockIdx.x * blockDim.x + threadIdx.x; idx < total;
         idx += gridDim.x * blockDim.x) {
        int j = idx & (DD - 1);
        float z  = S[idx];
        float mu = mean[j];
        float sc = expf(log_scale[j]);
        float ua = (z + 0.5f - mu) / sc;
        float ub = (z - 0.5f - mu) / sc;
        float la = fminf(ua, 0.f) - log1pf(expf(-fabsf(ua)));
        float lb = fminf(ub, 0.f) - log1pf(expf(-fabsf(ub)));
        float lp = la + logf(1.0f - expf(lb - la) + 1e-8f);
        local += lp;
    }
    __shared__ float red[256];
    red[threadIdx.x] = local;
    __syncthreads();
    for (int s = 128; s > 0; s >>= 1) {
        if (threadIdx.x < s) red[threadIdx.x] += red[threadIdx.x + s];
        __syncthreads();
    }
    if (threadIdx.x == 0) atomicAdd(out, -red[0] * (1.0f / (float)BQ));
}

extern "C" void kernel_launch(void* const* d_in, const int* in_sizes, int n_in,
                              void* d_out, int out_size, void* d_ws, size_t ws_size,
                              hipStream_t stream)
{
    const float* x   = (const float*)d_in[0];
    const float* W1  = (const float*)d_in[1];
    const float* b1  = (const float*)d_in[2];
    const float* W2  = (const float*)d_in[3];
    const float* b2  = (const float*)d_in[4];
    const float* W3  = (const float*)d_in[5];
    const float* b3  = (const float*)d_in[6];
    const float* mean = (const float*)d_in[7];
    const float* lsc  = (const float*)d_in[8];

    char* ws = (char*)d_ws;
    bf16_t* Wt1 = (bf16_t*)ws; ws += (size_t)NF * NH * D2 * 2;   // 16 MB (NxK = 2048x512)
    bf16_t* Wt2 = (bf16_t*)ws; ws += (size_t)NF * NH * NH * 2;   // 64 MB
    bf16_t* Wt3 = (bf16_t*)ws; ws += (size_t)NF * D2 * NH * 2;   // 16 MB (512x2048)
    float*  S   = (float*)ws;  ws += (size_t)BQ * DD * 4;        // 32 MB
    bf16_t* Ab  = (bf16_t*)ws; ws += (size_t)BQ * D2 * 2;        //  8 MB
    bf16_t* H1  = (bf16_t*)ws; ws += (size_t)BQ * NH * 2;        // 32 MB
    bf16_t* H2  = (bf16_t*)ws;                                   // 32 MB  (total 200 MB)

    hipMemsetAsync(d_out, 0, sizeof(float), stream);

    dim3 blk(256);
    // W1: (K=512, N=2048) -> Wt1 (2048x512)
    transpose_bf16<<<dim3(NH/32, D2/32, NF), blk, 0, stream>>>(W1, Wt1, D2, NH);
    // W2: (2048, 2048)
    transpose_bf16<<<dim3(NH/32, NH/32, NF), blk, 0, stream>>>(W2, Wt2, NH, NH);
    // W3: (K=2048, N=512) -> Wt3 (512x2048)
    transpose_bf16<<<dim3(D2/32, NH/32, NF), blk, 0, stream>>>(W3, Wt3, NH, D2);

    copy_x<<<BQ * DD / 4 / 256, blk, 0, stream>>>((const float4*)x, (float4*)S);

    for (int f = 0; f < NF; ++f) {
        int r = f & 1;
        prep_A<<<BQ * D2 / 256, blk, 0, stream>>>(S, Ab, r);
        // G1: (8192 x 512) @ (512 x 2048) -> H1
        gemm_kernel<0><<<dim3(NH/128, BQ/128), blk, 0, stream>>>(
            Ab, Wt1 + (size_t)f * NH * D2, b1 + (size_t)f * NH, H1, nullptr,
            NH, D2, 0);
        // G2: (8192 x 2048) @ (2048 x 2048) -> H2
        gemm_kernel<0><<<dim3(NH/128, BQ/128), blk, 0, stream>>>(
            H1, Wt2 + (size_t)f * NH * NH, b2 + (size_t)f * NH, H2, nullptr,
            NH, NH, 0);
        // G3: (8192 x 2048) @ (2048 x 512) -> in-place S update + reversal
        gemm_kernel<1><<<dim3(D2/128, BQ/128), blk, 0, stream>>>(
            H2, Wt3 + (size_t)f * D2 * NH, b3 + (size_t)f * D2, nullptr, S,
            D2, NH, r);
    }

    reduce_nll<<<2048, blk, 0, stream>>>(S, mean, lsc, (float*)d_out);
}

// Round 2
// 1926.624 us; speedup vs baseline: 1.0054x; 1.0054x over previous
//
#include <hip/hip_runtime.h>
#include <hip/hip_bf16.h>
#include <cmath>

// ---------------------------------------------------------------------------
// IntegerDiscreteFlow on MI355X (gfx950)
// B=8192, D=1024, d2=512, N=2048, F=8 steps.
// State S (8192x1024 f32) updated in place; the [:, ::-1] reversal is an
// orientation bit (logical j <-> stored 1023-j), flipped each step.
// GEMMs in bf16 MFMA 16x16x32, fp32 accumulate, m97-style 128x128x32 tiles.
// R2: XOR-swizzled LDS chunk placement (chunk q of row r stored at position
//     q ^ ((r>>1)&3)) to break the 8-way ds_read_b128 bank conflict.
// ---------------------------------------------------------------------------

typedef __bf16 bf16_t;
typedef bf16_t bf16x8 __attribute__((ext_vector_type(8)));
typedef float floatx4 __attribute__((ext_vector_type(4)));

#define BQ 8192
#define DD 1024
#define D2 512
#define NH 2048
#define NF 8

__device__ __forceinline__ void gload_lds16(const void* g, void* l) {
    __builtin_amdgcn_global_load_lds(
        (__attribute__((address_space(1))) void*)g,
        (__attribute__((address_space(3))) void*)l, 16, 0, 0);
}

// ---- weight convert+transpose: W (K x N f32, row-major) -> Wt (N x K bf16) --
__global__ __launch_bounds__(256)
void transpose_bf16(const float* __restrict__ W, bf16_t* __restrict__ Wt,
                    int K, int N) {
    __shared__ float tile[32][33];
    size_t fo = (size_t)blockIdx.z * K * N;
    int n0 = blockIdx.x * 32, k0 = blockIdx.y * 32;
    int tx = threadIdx.x & 31, ty = threadIdx.x >> 5;   // 32 x 8
    for (int i = 0; i < 4; i++)
        tile[ty + i*8][tx] = W[fo + (size_t)(k0 + ty + i*8) * N + n0 + tx];
    __syncthreads();
    for (int i = 0; i < 4; i++)
        Wt[fo + (size_t)(n0 + ty + i*8) * K + k0 + tx] = (bf16_t)tile[tx][ty + i*8];
}

// ---- copy x -> S (f32, vectorized) ----
__global__ __launch_bounds__(256)
void copy_x(const float4* __restrict__ x, float4* __restrict__ S) {
    int idx = blockIdx.x * blockDim.x + threadIdx.x;   // 2M threads
    S[idx] = x[idx];
}

// ---- build bf16 A operand (= logical xa) from S under orientation r ----
__global__ __launch_bounds__(256)
void prep_A(const float* __restrict__ S, bf16_t* __restrict__ Ab, int rflag) {
    int idx = blockIdx.x * blockDim.x + threadIdx.x;   // over 8192*512
    int m = idx >> 9;
    int j = idx & 511;
    int src = rflag ? (1023 - j) : j;
    Ab[idx] = (bf16_t)S[(size_t)m * DD + src];
}

// ---- GEMM: C = A(MxK bf16) @ B, B given transposed as Bt (NxK bf16) ----
// MODE 0: out = bf16( leaky_relu(acc + bias[n]) )
// MODE 1: S[m, slot(n)] += rint(acc + bias[n])   (in-place flow update)
template<int MODE>
__global__ __launch_bounds__(256)
void gemm_kernel(const bf16_t* __restrict__ A, const bf16_t* __restrict__ Bt,
                 const float* __restrict__ bias,
                 bf16_t* __restrict__ Cout, float* __restrict__ S,
                 int N, int K, int rflag)
{
    __shared__ __align__(16) bf16_t As[128 * 32];
    __shared__ __align__(16) bf16_t Bs[128 * 32];

    const int tid  = threadIdx.x;
    const int lane = tid & 63;
    const int wave = tid >> 6;
    const int wm   = wave >> 1;            // 0..1
    const int wn   = wave & 1;             // 0..1
    const int m0   = blockIdx.y * 128;
    const int n0   = blockIdx.x * 128;

    // staging: 256 threads x 16B = 4KB per issue; each 8KB tile = 2 issues.
    // XOR swizzle: LDS position p=tid&3 of row srow holds global chunk
    // q = p ^ ((srow>>1)&3)  -> the ds_read side spreads over all 8 bank
    // groups (2-way = free) instead of 2 (8-way).
    const int srow = tid >> 2;             // 0..63
    const int scol = ((tid & 3) ^ ((srow >> 1) & 3)) * 8;
    const bf16_t* ag0 = A  + (size_t)(m0 + srow)      * K + scol;
    const bf16_t* ag1 = A  + (size_t)(m0 + 64 + srow) * K + scol;
    const bf16_t* bg0 = Bt + (size_t)(n0 + srow)      * K + scol;
    const bf16_t* bg1 = Bt + (size_t)(n0 + 64 + srow) * K + scol;
    bf16_t* as0 = &As[tid * 8];
    bf16_t* as1 = &As[2048 + tid * 8];
    bf16_t* bs0 = &Bs[tid * 8];
    bf16_t* bs1 = &Bs[2048 + tid * 8];

    floatx4 acc[4][4];
#pragma unroll
    for (int i = 0; i < 4; i++)
#pragma unroll
        for (int j = 0; j < 4; j++)
            acc[i][j] = (floatx4){0.f, 0.f, 0.f, 0.f};

    const int fr = lane & 15;              // fragment row/col within 16
    // chunk q = lane>>4 lives at swizzled position q ^ ((fr>>1)&3); the
    // swizzle term depends only on fr (rows accessed differ by mult. of 16).
    const int fk = (((lane >> 4) ^ ((fr >> 1) & 3))) * 8;

    for (int k0 = 0; k0 < K; k0 += 32) {
        __syncthreads();
        gload_lds16(ag0, as0);
        gload_lds16(ag1, as1);
        gload_lds16(bg0, bs0);
        gload_lds16(bg1, bs1);
        ag0 += 32; ag1 += 32; bg0 += 32; bg1 += 32;
        __syncthreads();

        bf16x8 af[4], bff[4];
#pragma unroll
        for (int i = 0; i < 4; i++)
            af[i] = *(const bf16x8*)&As[(wm*64 + i*16 + fr) * 32 + fk];
#pragma unroll
        for (int j = 0; j < 4; j++)
            bff[j] = *(const bf16x8*)&Bs[(wn*64 + j*16 + fr) * 32 + fk];
#pragma unroll
        for (int i = 0; i < 4; i++)
#pragma unroll
            for (int j = 0; j < 4; j++)
                acc[i][j] = __builtin_amdgcn_mfma_f32_16x16x32_bf16(
                                af[i], bff[j], acc[i][j], 0, 0, 0);
    }

    // epilogue: C[row, col], col = lane&15, row = (lane>>4)*4 + r  (m89 layout)
    const int ccol  = lane & 15;
    const int crow4 = (lane >> 4) * 4;
#pragma unroll
    for (int j = 0; j < 4; j++) {
        int col = n0 + wn*64 + j*16 + ccol;
        float bj = bias[col];
        if (MODE == 0) {
#pragma unroll
            for (int i = 0; i < 4; i++) {
#pragma unroll
                for (int r = 0; r < 4; r++) {
                    int row = m0 + wm*64 + i*16 + crow4 + r;
                    float v = acc[i][j][r] + bj;
                    v = v >= 0.f ? v : 0.01f * v;
                    Cout[(size_t)row * N + col] = (bf16_t)v;
                }
            }
        } else {
            int slot = rflag ? (511 - col) : (512 + col);
#pragma unroll
            for (int i = 0; i < 4; i++) {
#pragma unroll
                for (int r = 0; r < 4; r++) {
                    int row = m0 + wm*64 + i*16 + crow4 + r;
                    float t = acc[i][j][r] + bj;
                    float* p = &S[(size_t)row * DD + slot];
                    *p = *p + rintf(t);
                }
            }
        }
    }
}

// ---- final discretized-logistic NLL reduction ----
__global__ __launch_bounds__(256)
void reduce_nll(const float* __restrict__ S, const float* __restrict__ mean,
                const float* __restrict__ log_scale, float* __restrict__ out)
{
    float local = 0.f;
    const int total = BQ * DD;
    for (int idx = blockIdx.x * blockDim.x + threadIdx.x; idx < total;
         idx += gridDim.x * blockDim.x) {
        int j = idx & (DD - 1);
        float z  = S[idx];
        float mu = mean[j];
        float sc = expf(log_scale[j]);
        float ua = (z + 0.5f - mu) / sc;
        float ub = (z - 0.5f - mu) / sc;
        float la = fminf(ua, 0.f) - log1pf(expf(-fabsf(ua)));
        float lb = fminf(ub, 0.f) - log1pf(expf(-fabsf(ub)));
        float lp = la + logf(1.0f - expf(lb - la) + 1e-8f);
        local += lp;
    }
    __shared__ float red[256];
    red[threadIdx.x] = local;
    __syncthreads();
    for (int s = 128; s > 0; s >>= 1) {
        if (threadIdx.x < s) red[threadIdx.x] += red[threadIdx.x + s];
        __syncthreads();
    }
    if (threadIdx.x == 0) atomicAdd(out, -red[0] * (1.0f / (float)BQ));
}

extern "C" void kernel_launch(void* const* d_in, const int* in_sizes, int n_in,
                              void* d_out, int out_size, void* d_ws, size_t ws_size,
                              hipStream_t stream)
{
    const float* x   = (const float*)d_in[0];
    const float* W1  = (const float*)d_in[1];
    const float* b1  = (const float*)d_in[2];
    const float* W2  = (const float*)d_in[3];
    const float* b2  = (const float*)d_in[4];
    const float* W3  = (const float*)d_in[5];
    const float* b3  = (const float*)d_in[6];
    const float* mean = (const float*)d_in[7];
    const float* lsc  = (const float*)d_in[8];

    char* ws = (char*)d_ws;
    bf16_t* Wt1 = (bf16_t*)ws; ws += (size_t)NF * NH * D2 * 2;   // 16 MB (NxK = 2048x512)
    bf16_t* Wt2 = (bf16_t*)ws; ws += (size_t)NF * NH * NH * 2;   // 64 MB
    bf16_t* Wt3 = (bf16_t*)ws; ws += (size_t)NF * D2 * NH * 2;   // 16 MB (512x2048)
    float*  S   = (float*)ws;  ws += (size_t)BQ * DD * 4;        // 32 MB
    bf16_t* Ab  = (bf16_t*)ws; ws += (size_t)BQ * D2 * 2;        //  8 MB
    bf16_t* H1  = (bf16_t*)ws; ws += (size_t)BQ * NH * 2;        // 32 MB
    bf16_t* H2  = (bf16_t*)ws;                                   // 32 MB  (total 200 MB)

    hipMemsetAsync(d_out, 0, sizeof(float), stream);

    dim3 blk(256);
    // W1: (K=512, N=2048) -> Wt1 (2048x512)
    transpose_bf16<<<dim3(NH/32, D2/32, NF), blk, 0, stream>>>(W1, Wt1, D2, NH);
    // W2: (2048, 2048)
    transpose_bf16<<<dim3(NH/32, NH/32, NF), blk, 0, stream>>>(W2, Wt2, NH, NH);
    // W3: (K=2048, N=512) -> Wt3 (512x2048)
    transpose_bf16<<<dim3(D2/32, NH/32, NF), blk, 0, stream>>>(W3, Wt3, NH, D2);

    copy_x<<<BQ * DD / 4 / 256, blk, 0, stream>>>((const float4*)x, (float4*)S);

    for (int f = 0; f < NF; ++f) {
        int r = f & 1;
        prep_A<<<BQ * D2 / 256, blk, 0, stream>>>(S, Ab, r);
        // G1: (8192 x 512) @ (512 x 2048) -> H1
        gemm_kernel<0><<<dim3(NH/128, BQ/128), blk, 0, stream>>>(
            Ab, Wt1 + (size_t)f * NH * D2, b1 + (size_t)f * NH, H1, nullptr,
            NH, D2, 0);
        // G2: (8192 x 2048) @ (2048 x 2048) -> H2
        gemm_kernel<0><<<dim3(NH/128, BQ/128), blk, 0, stream>>>(
            H1, Wt2 + (size_t)f * NH * NH, b2 + (size_t)f * NH, H2, nullptr,
            NH, NH, 0);
        // G3: (8192 x 2048) @ (2048 x 512) -> in-place S update + reversal
        gemm_kernel<1><<<dim3(D2/128, BQ/128), blk, 0, stream>>>(
            H2, Wt3 + (size_t)f * D2 * NH, b3 + (size_t)f * D2, nullptr, S,
            D2, NH, r);
    }

    reduce_nll<<<2048, blk, 0, stream>>>(S, mean, lsc, (float*)d_out);
}

// Round 3
// 1718.916 us; speedup vs baseline: 1.1269x; 1.1208x over previous
//
#include <hip/hip_runtime.h>
#include <hip/hip_bf16.h>
#include <cmath>

// ---------------------------------------------------------------------------
// IntegerDiscreteFlow on MI355X (gfx950)
// B=8192, D=1024, d2=512, N=2048, F=8 steps.
// State S (8192x1024 f32) updated in place; the [:, ::-1] reversal is an
// orientation bit (logical j <-> stored 1023-j), flipped each step.
// GEMMs in bf16 MFMA 16x16x32, fp32 accumulate, 128x128x32 tiles.
// R2: XOR-swizzled LDS chunk placement (conflicts 8.4M -> 0; neutral alone).
// R3: double-buffered LDS, prefetch-next-then-compute, ONE barrier per
//     K-iter (m99 structure) — hides the global_load_lds latency behind the
//     MFMA+ds_read phase instead of draining vmcnt(0) right after issue.
// ---------------------------------------------------------------------------

typedef __bf16 bf16_t;
typedef bf16_t bf16x8 __attribute__((ext_vector_type(8)));
typedef float floatx4 __attribute__((ext_vector_type(4)));

#define BQ 8192
#define DD 1024
#define D2 512
#define NH 2048
#define NF 8

__device__ __forceinline__ void gload_lds16(const void* g, void* l) {
    __builtin_amdgcn_global_load_lds(
        (__attribute__((address_space(1))) void*)g,
        (__attribute__((address_space(3))) void*)l, 16, 0, 0);
}

// ---- weight convert+transpose: W (K x N f32, row-major) -> Wt (N x K bf16) --
__global__ __launch_bounds__(256)
void transpose_bf16(const float* __restrict__ W, bf16_t* __restrict__ Wt,
                    int K, int N) {
    __shared__ float tile[32][33];
    size_t fo = (size_t)blockIdx.z * K * N;
    int n0 = blockIdx.x * 32, k0 = blockIdx.y * 32;
    int tx = threadIdx.x & 31, ty = threadIdx.x >> 5;   // 32 x 8
    for (int i = 0; i < 4; i++)
        tile[ty + i*8][tx] = W[fo + (size_t)(k0 + ty + i*8) * N + n0 + tx];
    __syncthreads();
    for (int i = 0; i < 4; i++)
        Wt[fo + (size_t)(n0 + ty + i*8) * K + k0 + tx] = (bf16_t)tile[tx][ty + i*8];
}

// ---- copy x -> S (f32, vectorized) ----
__global__ __launch_bounds__(256)
void copy_x(const float4* __restrict__ x, float4* __restrict__ S) {
    int idx = blockIdx.x * blockDim.x + threadIdx.x;   // 2M threads
    S[idx] = x[idx];
}

// ---- build bf16 A operand (= logical xa) from S under orientation r ----
__global__ __launch_bounds__(256)
void prep_A(const float* __restrict__ S, bf16_t* __restrict__ Ab, int rflag) {
    int idx = blockIdx.x * blockDim.x + threadIdx.x;   // over 8192*512
    int m = idx >> 9;
    int j = idx & 511;
    int src = rflag ? (1023 - j) : j;
    Ab[idx] = (bf16_t)S[(size_t)m * DD + src];
}

// ---- GEMM: C = A(MxK bf16) @ B, B given transposed as Bt (NxK bf16) ----
// MODE 0: out = bf16( leaky_relu(acc + bias[n]) )
// MODE 1: S[m, slot(n)] += rint(acc + bias[n])   (in-place flow update)
template<int MODE, int K>
__global__ __launch_bounds__(256)
void gemm_kernel(const bf16_t* __restrict__ A, const bf16_t* __restrict__ Bt,
                 const float* __restrict__ bias,
                 bf16_t* __restrict__ Cout, float* __restrict__ S,
                 int N, int rflag)
{
    __shared__ __align__(16) bf16_t As[2][128 * 32];
    __shared__ __align__(16) bf16_t Bs[2][128 * 32];

    const int tid  = threadIdx.x;
    const int lane = tid & 63;
    const int wave = tid >> 6;
    const int wm   = wave >> 1;            // 0..1
    const int wn   = wave & 1;             // 0..1
    const int m0   = blockIdx.y * 128;
    const int n0   = blockIdx.x * 128;

    // staging: XOR swizzle — LDS position p=tid&3 of row srow holds global
    // chunk q = p ^ ((srow>>1)&3); ds_read side spreads over all 8 bank groups.
    const int srow = tid >> 2;             // 0..63
    const int scol = ((tid & 3) ^ ((srow >> 1) & 3)) * 8;
    const bf16_t* ag0 = A  + (size_t)(m0 + srow)      * K + scol;
    const bf16_t* ag1 = A  + (size_t)(m0 + 64 + srow) * K + scol;
    const bf16_t* bg0 = Bt + (size_t)(n0 + srow)      * K + scol;
    const bf16_t* bg1 = Bt + (size_t)(n0 + 64 + srow) * K + scol;

    floatx4 acc[4][4];
#pragma unroll
    for (int i = 0; i < 4; i++)
#pragma unroll
        for (int j = 0; j < 4; j++)
            acc[i][j] = (floatx4){0.f, 0.f, 0.f, 0.f};

    const int fr = lane & 15;              // fragment row/col within 16
    const int fk = ((lane >> 4) ^ ((fr >> 1) & 3)) * 8;   // swizzled chunk pos

    // prologue: stage tile 0 into buffer 0
    gload_lds16(ag0, &As[0][tid * 8]);
    gload_lds16(ag1, &As[0][2048 + tid * 8]);
    gload_lds16(bg0, &Bs[0][tid * 8]);
    gload_lds16(bg1, &Bs[0][2048 + tid * 8]);
    ag0 += 32; ag1 += 32; bg0 += 32; bg1 += 32;

    constexpr int T = K / 32;              // number of K-tiles
#pragma unroll 2
    for (int it = 1; it < T; ++it) {
        __syncthreads();                   // drains tile it-1 loads (issued one
                                           // full compute-phase ago) + guards buf reuse
        const int nb = it & 1;             // buffer receiving tile `it`
        const int cb = nb ^ 1;             // buffer holding tile `it-1`
        gload_lds16(ag0, &As[nb][tid * 8]);
        gload_lds16(ag1, &As[nb][2048 + tid * 8]);
        gload_lds16(bg0, &Bs[nb][tid * 8]);
        gload_lds16(bg1, &Bs[nb][2048 + tid * 8]);
        ag0 += 32; ag1 += 32; bg0 += 32; bg1 += 32;

        bf16x8 af[4], bff[4];
#pragma unroll
        for (int i = 0; i < 4; i++)
            af[i] = *(const bf16x8*)&As[cb][(wm*64 + i*16 + fr) * 32 + fk];
#pragma unroll
        for (int j = 0; j < 4; j++)
            bff[j] = *(const bf16x8*)&Bs[cb][(wn*64 + j*16 + fr) * 32 + fk];
#pragma unroll
        for (int i = 0; i < 4; i++)
#pragma unroll
            for (int j = 0; j < 4; j++)
                acc[i][j] = __builtin_amdgcn_mfma_f32_16x16x32_bf16(
                                af[i], bff[j], acc[i][j], 0, 0, 0);
    }
    __syncthreads();                       // drain last tile's loads
    {
        const int cb = (T - 1) & 1;
        bf16x8 af[4], bff[4];
#pragma unroll
        for (int i = 0; i < 4; i++)
            af[i] = *(const bf16x8*)&As[cb][(wm*64 + i*16 + fr) * 32 + fk];
#pragma unroll
        for (int j = 0; j < 4; j++)
            bff[j] = *(const bf16x8*)&Bs[cb][(wn*64 + j*16 + fr) * 32 + fk];
#pragma unroll
        for (int i = 0; i < 4; i++)
#pragma unroll
            for (int j = 0; j < 4; j++)
                acc[i][j] = __builtin_amdgcn_mfma_f32_16x16x32_bf16(
                                af[i], bff[j], acc[i][j], 0, 0, 0);
    }

    // epilogue: C[row, col], col = lane&15, row = (lane>>4)*4 + r  (m89 layout)
    const int ccol  = lane & 15;
    const int crow4 = (lane >> 4) * 4;
#pragma unroll
    for (int j = 0; j < 4; j++) {
        int col = n0 + wn*64 + j*16 + ccol;
        float bj = bias[col];
        if (MODE == 0) {
#pragma unroll
            for (int i = 0; i < 4; i++) {
#pragma unroll
                for (int r = 0; r < 4; r++) {
                    int row = m0 + wm*64 + i*16 + crow4 + r;
                    float v = acc[i][j][r] + bj;
                    v = v >= 0.f ? v : 0.01f * v;
                    Cout[(size_t)row * N + col] = (bf16_t)v;
                }
            }
        } else {
            int slot = rflag ? (511 - col) : (512 + col);
#pragma unroll
            for (int i = 0; i < 4; i++) {
#pragma unroll
                for (int r = 0; r < 4; r++) {
                    int row = m0 + wm*64 + i*16 + crow4 + r;
                    float t = acc[i][j][r] + bj;
                    float* p = &S[(size_t)row * DD + slot];
                    *p = *p + rintf(t);
                }
            }
        }
    }
}

// ---- final discretized-logistic NLL reduction ----
__global__ __launch_bounds__(256)
void reduce_nll(const float* __restrict__ S, const float* __restrict__ mean,
                const float* __restrict__ log_scale, float* __restrict__ out)
{
    float local = 0.f;
    const int total = BQ * DD;
    for (int idx = blockIdx.x * blockDim.x + threadIdx.x; idx < total;
         idx += gridDim.x * blockDim.x) {
        int j = idx & (DD - 1);
        float z  = S[idx];
        float mu = mean[j];
        float sc = expf(log_scale[j]);
        float ua = (z + 0.5f - mu) / sc;
        float ub = (z - 0.5f - mu) / sc;
        float la = fminf(ua, 0.f) - log1pf(expf(-fabsf(ua)));
        float lb = fminf(ub, 0.f) - log1pf(expf(-fabsf(ub)));
        float lp = la + logf(1.0f - expf(lb - la) + 1e-8f);
        local += lp;
    }
    __shared__ float red[256];
    red[threadIdx.x] = local;
    __syncthreads();
    for (int s = 128; s > 0; s >>= 1) {
        if (threadIdx.x < s) red[threadIdx.x] += red[threadIdx.x + s];
        __syncthreads();
    }
    if (threadIdx.x == 0) atomicAdd(out, -red[0] * (1.0f / (float)BQ));
}

extern "C" void kernel_launch(void* const* d_in, const int* in_sizes, int n_in,
                              void* d_out, int out_size, void* d_ws, size_t ws_size,
                              hipStream_t stream)
{
    const float* x   = (const float*)d_in[0];
    const float* W1  = (const float*)d_in[1];
    const float* b1  = (const float*)d_in[2];
    const float* W2  = (const float*)d_in[3];
    const float* b2  = (const float*)d_in[4];
    const float* W3  = (const float*)d_in[5];
    const float* b3  = (const float*)d_in[6];
    const float* mean = (const float*)d_in[7];
    const float* lsc  = (const float*)d_in[8];

    char* ws = (char*)d_ws;
    bf16_t* Wt1 = (bf16_t*)ws; ws += (size_t)NF * NH * D2 * 2;   // 16 MB (NxK = 2048x512)
    bf16_t* Wt2 = (bf16_t*)ws; ws += (size_t)NF * NH * NH * 2;   // 64 MB
    bf16_t* Wt3 = (bf16_t*)ws; ws += (size_t)NF * D2 * NH * 2;   // 16 MB (512x2048)
    float*  S   = (float*)ws;  ws += (size_t)BQ * DD * 4;        // 32 MB
    bf16_t* Ab  = (bf16_t*)ws; ws += (size_t)BQ * D2 * 2;        //  8 MB
    bf16_t* H1  = (bf16_t*)ws; ws += (size_t)BQ * NH * 2;        // 32 MB
    bf16_t* H2  = (bf16_t*)ws;                                   // 32 MB  (total 200 MB)

    hipMemsetAsync(d_out, 0, sizeof(float), stream);

    dim3 blk(256);
    // W1: (K=512, N=2048) -> Wt1 (2048x512)
    transpose_bf16<<<dim3(NH/32, D2/32, NF), blk, 0, stream>>>(W1, Wt1, D2, NH);
    // W2: (2048, 2048)
    transpose_bf16<<<dim3(NH/32, NH/32, NF), blk, 0, stream>>>(W2, Wt2, NH, NH);
    // W3: (K=2048, N=512) -> Wt3 (512x2048)
    transpose_bf16<<<dim3(D2/32, NH/32, NF), blk, 0, stream>>>(W3, Wt3, NH, D2);

    copy_x<<<BQ * DD / 4 / 256, blk, 0, stream>>>((const float4*)x, (float4*)S);

    for (int f = 0; f < NF; ++f) {
        int r = f & 1;
        prep_A<<<BQ * D2 / 256, blk, 0, stream>>>(S, Ab, r);
        // G1: (8192 x 512) @ (512 x 2048) -> H1
        gemm_kernel<0, D2><<<dim3(NH/128, BQ/128), blk, 0, stream>>>(
            Ab, Wt1 + (size_t)f * NH * D2, b1 + (size_t)f * NH, H1, nullptr,
            NH, 0);
        // G2: (8192 x 2048) @ (2048 x 2048) -> H2
        gemm_kernel<0, NH><<<dim3(NH/128, BQ/128), blk, 0, stream>>>(
            H1, Wt2 + (size_t)f * NH * NH, b2 + (size_t)f * NH, H2, nullptr,
            NH, 0);
        // G3: (8192 x 2048) @ (2048 x 512) -> in-place S update + reversal
        gemm_kernel<1, NH><<<dim3(D2/128, BQ/128), blk, 0, stream>>>(
            H2, Wt3 + (size_t)f * D2 * NH, b3 + (size_t)f * D2, nullptr, S,
            D2, r);
    }

    reduce_nll<<<2048, blk, 0, stream>>>(S, mean, lsc, (float*)d_out);
}

// Round 4
// 1619.075 us; speedup vs baseline: 1.1964x; 1.0617x over previous
//
#include <hip/hip_runtime.h>
#include <hip/hip_bf16.h>
#include <cmath>

// ---------------------------------------------------------------------------
// IntegerDiscreteFlow on MI355X (gfx950)
// B=8192, D=1024, d2=512, N=2048, F=8 steps.
// State S (8192x1024 f32) updated in place; the [:, ::-1] reversal is an
// orientation bit (logical j <-> stored 1023-j), flipped each step.
// GEMMs in bf16 MFMA 16x16x32, fp32 accumulate, 128x128 tiles.
// R2: XOR-swizzled LDS placement (bank conflicts 8.4M -> 0).
// R3: double-buffered LDS, one barrier per K-iter.
// R4: BK=64 (compute phase ~2x between barriers -> hides DMA latency better);
//     G3 epilogue emits next step's A operand (xa_next = reverse(yb)) so
//     prep_A runs only once, for step 0.
// ---------------------------------------------------------------------------

typedef __bf16 bf16_t;
typedef bf16_t bf16x8 __attribute__((ext_vector_type(8)));
typedef float floatx4 __attribute__((ext_vector_type(4)));

#define BQ 8192
#define DD 1024
#define D2 512
#define NH 2048
#define NF 8

__device__ __forceinline__ void gload_lds16(const void* g, void* l) {
    __builtin_amdgcn_global_load_lds(
        (__attribute__((address_space(1))) void*)g,
        (__attribute__((address_space(3))) void*)l, 16, 0, 0);
}

// ---- weight convert+transpose: W (K x N f32, row-major) -> Wt (N x K bf16) --
__global__ __launch_bounds__(256)
void transpose_bf16(const float* __restrict__ W, bf16_t* __restrict__ Wt,
                    int K, int N) {
    __shared__ float tile[32][33];
    size_t fo = (size_t)blockIdx.z * K * N;
    int n0 = blockIdx.x * 32, k0 = blockIdx.y * 32;
    int tx = threadIdx.x & 31, ty = threadIdx.x >> 5;   // 32 x 8
    for (int i = 0; i < 4; i++)
        tile[ty + i*8][tx] = W[fo + (size_t)(k0 + ty + i*8) * N + n0 + tx];
    __syncthreads();
    for (int i = 0; i < 4; i++)
        Wt[fo + (size_t)(n0 + ty + i*8) * K + k0 + tx] = (bf16_t)tile[tx][ty + i*8];
}

// ---- copy x -> S (f32, vectorized) ----
__global__ __launch_bounds__(256)
void copy_x(const float4* __restrict__ x, float4* __restrict__ S) {
    int idx = blockIdx.x * blockDim.x + threadIdx.x;   // 2M threads
    S[idx] = x[idx];
}

// ---- build bf16 A operand (= logical xa) from S, identity orientation ----
__global__ __launch_bounds__(256)
void prep_A(const float* __restrict__ S, bf16_t* __restrict__ Ab) {
    int idx = blockIdx.x * blockDim.x + threadIdx.x;   // over 8192*512
    int m = idx >> 9;
    int j = idx & 511;
    Ab[idx] = (bf16_t)S[(size_t)m * DD + j];
}

// ---- GEMM: C = A(MxK bf16) @ B, B given transposed as Bt (NxK bf16) ----
// MODE 0: out = bf16( leaky_relu(acc + bias[n]) )
// MODE 1: S[m, slot(n)] += rint(acc + bias[n]); Abn[m, 511-n] = new value
// BK=64, double-buffered LDS, one barrier per K-iter.
template<int MODE, int K>
__global__ __launch_bounds__(256, 2)
void gemm_kernel(const bf16_t* __restrict__ A, const bf16_t* __restrict__ Bt,
                 const float* __restrict__ bias,
                 bf16_t* __restrict__ Cout, float* __restrict__ S,
                 bf16_t* __restrict__ Abn,
                 int N, int rflag)
{
    // 128 rows x 64 cols bf16 = 16 KB per operand per buffer; 64 KB total.
    __shared__ __align__(16) bf16_t As[2][128 * 64];
    __shared__ __align__(16) bf16_t Bs[2][128 * 64];

    const int tid  = threadIdx.x;
    const int lane = tid & 63;
    const int wave = tid >> 6;
    const int wm   = wave >> 1;            // 0..1
    const int wn   = wave & 1;             // 0..1
    const int m0   = blockIdx.y * 128;
    const int n0   = blockIdx.x * 128;

    // DMA staging: thread t covers row (t>>3), chunk position p = t&7 of the
    // 8x16B row; the global chunk fetched is q = p ^ (row&7) (XOR swizzle).
    // LDS dst offset = t*8 elems (linear, as the DMA requires); 4 issues of
    // 32 rows each cover the 128-row tile.
    const int srow = tid >> 3;             // 0..31
    const int sq   = ((tid & 7) ^ (srow & 7)) * 8;
    const bf16_t* agp = A  + (size_t)(m0 + srow) * K + sq;
    const bf16_t* bgp = Bt + (size_t)(n0 + srow) * K + sq;

    floatx4 acc[4][4];
#pragma unroll
    for (int i = 0; i < 4; i++)
#pragma unroll
        for (int j = 0; j < 4; j++)
            acc[i][j] = (floatx4){0.f, 0.f, 0.f, 0.f};

    // fragment read indices: row rr = wm*64+i*16+(lane&15); chunk for kstep s
    // is c = s*4 + (lane>>4), stored at position c ^ (rr&7) = c ^ (lane&7).
    const int fr = lane & 15;
    const int fq = lane >> 4;
    const int fx = lane & 7;

    // prologue: tile 0 into buffer 0
#pragma unroll
    for (int u = 0; u < 4; u++) {
        gload_lds16(agp + (size_t)(u*32) * K, &As[0][u*2048 + tid*8]);
        gload_lds16(bgp + (size_t)(u*32) * K, &Bs[0][u*2048 + tid*8]);
    }
    agp += 64; bgp += 64;

    constexpr int T = K / 64;              // number of K-tiles
#pragma unroll 2
    for (int it = 1; it < T; ++it) {
        __syncthreads();                   // drains tile it-1 DMA + guards buf
        const int nb = it & 1;
        const int cb = nb ^ 1;
#pragma unroll
        for (int u = 0; u < 4; u++) {
            gload_lds16(agp + (size_t)(u*32) * K, &As[nb][u*2048 + tid*8]);
            gload_lds16(bgp + (size_t)(u*32) * K, &Bs[nb][u*2048 + tid*8]);
        }
        agp += 64; bgp += 64;

#pragma unroll
        for (int s = 0; s < 2; s++) {
            const int kc = ((s*4 + fq) ^ fx) * 8;
            bf16x8 af[4], bff[4];
#pragma unroll
            for (int i = 0; i < 4; i++)
                af[i] = *(const bf16x8*)&As[cb][(wm*64 + i*16 + fr) * 64 + kc];
#pragma unroll
            for (int j = 0; j < 4; j++)
                bff[j] = *(const bf16x8*)&Bs[cb][(wn*64 + j*16 + fr) * 64 + kc];
#pragma unroll
            for (int i = 0; i < 4; i++)
#pragma unroll
                for (int j = 0; j < 4; j++)
                    acc[i][j] = __builtin_amdgcn_mfma_f32_16x16x32_bf16(
                                    af[i], bff[j], acc[i][j], 0, 0, 0);
        }
    }
    __syncthreads();                       // drain last tile's DMA
    {
        const int cb = (T - 1) & 1;
#pragma unroll
        for (int s = 0; s < 2; s++) {
            const int kc = ((s*4 + fq) ^ fx) * 8;
            bf16x8 af[4], bff[4];
#pragma unroll
            for (int i = 0; i < 4; i++)
                af[i] = *(const bf16x8*)&As[cb][(wm*64 + i*16 + fr) * 64 + kc];
#pragma unroll
            for (int j = 0; j < 4; j++)
                bff[j] = *(const bf16x8*)&Bs[cb][(wn*64 + j*16 + fr) * 64 + kc];
#pragma unroll
            for (int i = 0; i < 4; i++)
#pragma unroll
                for (int j = 0; j < 4; j++)
                    acc[i][j] = __builtin_amdgcn_mfma_f32_16x16x32_bf16(
                                    af[i], bff[j], acc[i][j], 0, 0, 0);
        }
    }

    // epilogue: C[row, col], col = lane&15, row = (lane>>4)*4 + r  (m89 layout)
    const int ccol  = lane & 15;
    const int crow4 = (lane >> 4) * 4;
#pragma unroll
    for (int j = 0; j < 4; j++) {
        int col = n0 + wn*64 + j*16 + ccol;
        float bj = bias[col];
        if (MODE == 0) {
#pragma unroll
            for (int i = 0; i < 4; i++) {
#pragma unroll
                for (int r = 0; r < 4; r++) {
                    int row = m0 + wm*64 + i*16 + crow4 + r;
                    float v = acc[i][j][r] + bj;
                    v = v >= 0.f ? v : 0.01f * v;
                    Cout[(size_t)row * N + col] = (bf16_t)v;
                }
            }
        } else {
            int slot = rflag ? (511 - col) : (512 + col);
            int aj   = 511 - col;          // next step's xa = reverse(yb)
#pragma unroll
            for (int i = 0; i < 4; i++) {
#pragma unroll
                for (int r = 0; r < 4; r++) {
                    int row = m0 + wm*64 + i*16 + crow4 + r;
                    float t = acc[i][j][r] + bj;
                    float nv = S[(size_t)row * DD + slot] + rintf(t);
                    S[(size_t)row * DD + slot] = nv;
                    Abn[(size_t)row * D2 + aj] = (bf16_t)nv;
                }
            }
        }
    }
}

// ---- final discretized-logistic NLL reduction ----
__global__ __launch_bounds__(256)
void reduce_nll(const float* __restrict__ S, const float* __restrict__ mean,
                const float* __restrict__ log_scale, float* __restrict__ out)
{
    float local = 0.f;
    const int total = BQ * DD;
    for (int idx = blockIdx.x * blockDim.x + threadIdx.x; idx < total;
         idx += gridDim.x * blockDim.x) {
        int j = idx & (DD - 1);
        float z  = S[idx];
        float mu = mean[j];
        float sc = expf(log_scale[j]);
        float ua = (z + 0.5f - mu) / sc;
        float ub = (z - 0.5f - mu) / sc;
        float la = fminf(ua, 0.f) - log1pf(expf(-fabsf(ua)));
        float lb = fminf(ub, 0.f) - log1pf(expf(-fabsf(ub)));
        float lp = la + logf(1.0f - expf(lb - la) + 1e-8f);
        local += lp;
    }
    __shared__ float red[256];
    red[threadIdx.x] = local;
    __syncthreads();
    for (int s = 128; s > 0; s >>= 1) {
        if (threadIdx.x < s) red[threadIdx.x] += red[threadIdx.x + s];
        __syncthreads();
    }
    if (threadIdx.x == 0) atomicAdd(out, -red[0] * (1.0f / (float)BQ));
}

extern "C" void kernel_launch(void* const* d_in, const int* in_sizes, int n_in,
                              void* d_out, int out_size, void* d_ws, size_t ws_size,
                              hipStream_t stream)
{
    const float* x   = (const float*)d_in[0];
    const float* W1  = (const float*)d_in[1];
    const float* b1  = (const float*)d_in[2];
    const float* W2  = (const float*)d_in[3];
    const float* b2  = (const float*)d_in[4];
    const float* W3  = (const float*)d_in[5];
    const float* b3  = (const float*)d_in[6];
    const float* mean = (const float*)d_in[7];
    const float* lsc  = (const float*)d_in[8];

    char* ws = (char*)d_ws;
    bf16_t* Wt1 = (bf16_t*)ws; ws += (size_t)NF * NH * D2 * 2;   // 16 MB (NxK = 2048x512)
    bf16_t* Wt2 = (bf16_t*)ws; ws += (size_t)NF * NH * NH * 2;   // 64 MB
    bf16_t* Wt3 = (bf16_t*)ws; ws += (size_t)NF * D2 * NH * 2;   // 16 MB (512x2048)
    float*  S   = (float*)ws;  ws += (size_t)BQ * DD * 4;        // 32 MB
    bf16_t* Ab  = (bf16_t*)ws; ws += (size_t)BQ * D2 * 2;        //  8 MB
    bf16_t* H1  = (bf16_t*)ws; ws += (size_t)BQ * NH * 2;        // 32 MB
    bf16_t* H2  = (bf16_t*)ws;                                   // 32 MB  (total 200 MB)

    hipMemsetAsync(d_out, 0, sizeof(float), stream);

    dim3 blk(256);
    // W1: (K=512, N=2048) -> Wt1 (2048x512)
    transpose_bf16<<<dim3(NH/32, D2/32, NF), blk, 0, stream>>>(W1, Wt1, D2, NH);
    // W2: (2048, 2048)
    transpose_bf16<<<dim3(NH/32, NH/32, NF), blk, 0, stream>>>(W2, Wt2, NH, NH);
    // W3: (K=2048, N=512) -> Wt3 (512x2048)
    transpose_bf16<<<dim3(D2/32, NH/32, NF), blk, 0, stream>>>(W3, Wt3, NH, D2);

    copy_x<<<BQ * DD / 4 / 256, blk, 0, stream>>>((const float4*)x, (float4*)S);
    prep_A<<<BQ * D2 / 256, blk, 0, stream>>>(S, Ab);   // step 0 only

    for (int f = 0; f < NF; ++f) {
        int r = f & 1;
        // G1: (8192 x 512) @ (512 x 2048) -> H1
        gemm_kernel<0, D2><<<dim3(NH/128, BQ/128), blk, 0, stream>>>(
            Ab, Wt1 + (size_t)f * NH * D2, b1 + (size_t)f * NH, H1, nullptr,
            nullptr, NH, 0);
        // G2: (8192 x 2048) @ (2048 x 2048) -> H2
        gemm_kernel<0, NH><<<dim3(NH/128, BQ/128), blk, 0, stream>>>(
            H1, Wt2 + (size_t)f * NH * NH, b2 + (size_t)f * NH, H2, nullptr,
            nullptr, NH, 0);
        // G3: (8192 x 2048) @ (2048 x 512) -> in-place S update + next-A emit
        gemm_kernel<1, NH><<<dim3(D2/128, BQ/128), blk, 0, stream>>>(
            H2, Wt3 + (size_t)f * D2 * NH, b3 + (size_t)f * D2, nullptr, S,
            Ab, D2, r);
    }

    reduce_nll<<<2048, blk, 0, stream>>>(S, mean, lsc, (float*)d_out);
}

// Round 5
// 1616.687 us; speedup vs baseline: 1.1981x; 1.0015x over previous
//
#include <hip/hip_runtime.h>
#include <hip/hip_bf16.h>
#include <cmath>

// ---------------------------------------------------------------------------
// IntegerDiscreteFlow on MI355X (gfx950)
// B=8192, D=1024, d2=512, N=2048, F=8 steps.
// State S (8192x1024 f32) updated in place; the [:, ::-1] reversal is an
// orientation bit (logical j <-> stored 1023-j), flipped each step.
// GEMMs in bf16 MFMA 16x16x32, fp32 accumulate.
// R2: XOR-swizzled LDS placement (bank conflicts -> 0).
// R3: double-buffered LDS, one barrier per K-iter.
// R4: BK=64; G3 epilogue emits next step's A operand (prep_A once).
// R5: AITER-style pipeline: ring-3 LDS buffers (BK=32, 48 KB), DMA issued
//     BEFORE s_waitcnt vmcnt(NDMA) + raw s_barrier -> newest tile's loads
//     stay in flight across the barrier (never vmcnt(0) in steady state).
//     3 blocks/CU. G3 uses TM=64 tiles (512 blocks instead of 256).
// ---------------------------------------------------------------------------

typedef __bf16 bf16_t;
typedef bf16_t bf16x8 __attribute__((ext_vector_type(8)));
typedef float floatx4 __attribute__((ext_vector_type(4)));

#define BQ 8192
#define DD 1024
#define D2 512
#define NH 2048
#define NF 8

__device__ __forceinline__ void gload_lds16(const void* g, void* l) {
    __builtin_amdgcn_global_load_lds(
        (__attribute__((address_space(1))) void*)g,
        (__attribute__((address_space(3))) void*)l, 16, 0, 0);
}

// ---- weight convert+transpose: W (K x N f32, row-major) -> Wt (N x K bf16) --
__global__ __launch_bounds__(256)
void transpose_bf16(const float* __restrict__ W, bf16_t* __restrict__ Wt,
                    int K, int N) {
    __shared__ float tile[32][33];
    size_t fo = (size_t)blockIdx.z * K * N;
    int n0 = blockIdx.x * 32, k0 = blockIdx.y * 32;
    int tx = threadIdx.x & 31, ty = threadIdx.x >> 5;   // 32 x 8
    for (int i = 0; i < 4; i++)
        tile[ty + i*8][tx] = W[fo + (size_t)(k0 + ty + i*8) * N + n0 + tx];
    __syncthreads();
    for (int i = 0; i < 4; i++)
        Wt[fo + (size_t)(n0 + ty + i*8) * K + k0 + tx] = (bf16_t)tile[tx][ty + i*8];
}

// ---- copy x -> S (f32, vectorized) ----
__global__ __launch_bounds__(256)
void copy_x(const float4* __restrict__ x, float4* __restrict__ S) {
    int idx = blockIdx.x * blockDim.x + threadIdx.x;   // 2M threads
    S[idx] = x[idx];
}

// ---- build bf16 A operand (= logical xa) from S, identity orientation ----
__global__ __launch_bounds__(256)
void prep_A(const float* __restrict__ S, bf16_t* __restrict__ Ab) {
    int idx = blockIdx.x * blockDim.x + threadIdx.x;   // over 8192*512
    int m = idx >> 9;
    int j = idx & 511;
    Ab[idx] = (bf16_t)S[(size_t)m * DD + j];
}

// ---- GEMM: C = A(MxK bf16) @ B, B given transposed as Bt (NxK bf16) ----
// Tile TM x 128, BK=32, ring-3 LDS pipeline, 4 waves (2x2).
// MODE 0: out = bf16( leaky_relu(acc + bias[n]) )
// MODE 1: S[m, slot(n)] += rint(acc + bias[n]); Abn[m, 511-n] = new value
template<int MODE, int K, int TM>
__global__ __launch_bounds__(256, 3)
void gemm_kernel(const bf16_t* __restrict__ A, const bf16_t* __restrict__ Bt,
                 const float* __restrict__ bias,
                 bf16_t* __restrict__ Cout, float* __restrict__ S,
                 bf16_t* __restrict__ Abn,
                 int N, int rflag)
{
    constexpr int IM   = TM / 32;          // i-fragments per wave
    constexpr int NA   = TM / 64;          // A DMA instrs per tile
    constexpr int NDMA = NA + 2;           // DMA instrs per tile (A + B)
    constexpr int T    = K / 32;           // K-tiles
    static_assert((T - 1) % 3 == 0, "pipeline triple-unroll needs (T-1)%3==0");

    __shared__ __align__(16) bf16_t As[3][TM * 32];
    __shared__ __align__(16) bf16_t Bs[3][128 * 32];

    const int tid  = threadIdx.x;
    const int lane = tid & 63;
    const int wave = tid >> 6;
    const int wm   = wave >> 1;            // 0..1
    const int wn   = wave & 1;             // 0..1
    const int m0   = blockIdx.y * TM;
    const int n0   = blockIdx.x * 128;

    // Staging map (per DMA instr u): thread t -> row u*64 + (t>>2), chunk
    // position p = t&3; global chunk fetched q = p ^ ((row>>1)&3) (XOR
    // swizzle; u*64 doesn't change (row>>1)&3). LDS dst = u*2048 + t*8 elems.
    const int srow = tid >> 2;
    const int sq   = ((tid & 3) ^ ((srow >> 1) & 3)) * 8;
    const bf16_t* agp = A  + (size_t)(m0 + srow) * K + sq;
    const bf16_t* bgp = Bt + (size_t)(n0 + srow) * K + sq;

    floatx4 acc[IM][4];
#pragma unroll
    for (int i = 0; i < IM; i++)
#pragma unroll
        for (int j = 0; j < 4; j++)
            acc[i][j] = (floatx4){0.f, 0.f, 0.f, 0.f};

    // Fragment read: row rr = base + (lane&15) (base mult. of 16), chunk
    // c = lane>>4 stored at position c ^ ((rr>>1)&3) = c ^ ((lane>>1)&3).
    const int fr  = lane & 15;
    const int fp8 = ((lane >> 4) ^ ((lane >> 1) & 3)) * 8;

    bf16x8 af[IM], bff[4];

#define ISSUE_TILE(NB)                                                       \
    {                                                                        \
        _Pragma("unroll")                                                    \
        for (int u = 0; u < NA; u++)                                         \
            gload_lds16(agp + (size_t)(u*64) * K, &As[NB][u*2048 + tid*8]);  \
        _Pragma("unroll")                                                    \
        for (int u = 0; u < 2; u++)                                          \
            gload_lds16(bgp + (size_t)(u*64) * K, &Bs[NB][u*2048 + tid*8]);  \
        agp += 32; bgp += 32;                                                \
    }

#define COMPUTE(CB)                                                          \
    {                                                                        \
        _Pragma("unroll")                                                    \
        for (int i = 0; i < IM; i++)                                         \
            af[i] = *(const bf16x8*)&As[CB][(wm*(TM/2) + i*16 + fr)*32 + fp8];\
        _Pragma("unroll")                                                    \
        for (int j = 0; j < 4; j++)                                          \
            bff[j] = *(const bf16x8*)&Bs[CB][(wn*64 + j*16 + fr)*32 + fp8];  \
        _Pragma("unroll")                                                    \
        for (int i = 0; i < IM; i++)                                         \
            _Pragma("unroll")                                                \
            for (int j = 0; j < 4; j++)                                      \
                acc[i][j] = __builtin_amdgcn_mfma_f32_16x16x32_bf16(         \
                                af[i], bff[j], acc[i][j], 0, 0, 0);          \
    }

#define PIPE_STEP(NB, CB)                                                    \
    {                                                                        \
        ISSUE_TILE(NB);                                                      \
        __builtin_amdgcn_s_waitcnt(0x0F70 | NDMA);  /* prev tile landed */   \
        __builtin_amdgcn_s_barrier();                                        \
        COMPUTE(CB);                                                         \
    }

    // prologue: tile 0 -> buf 0
    ISSUE_TILE(0);

    // steady state: tiles it = 3g+1, 3g+2, 3g+3 -> bufs 1, 2, 0
#pragma unroll 1
    for (int g = 0; g < (T - 1) / 3; ++g) {
        PIPE_STEP(1, 0);
        PIPE_STEP(2, 1);
        PIPE_STEP(0, 2);
    }
    // tail: compute tile T-1, which lives in buf (T-1)%3 == 0
    __builtin_amdgcn_s_waitcnt(0x0F70);            // vmcnt(0)
    __builtin_amdgcn_s_barrier();
    COMPUTE(0);

#undef PIPE_STEP
#undef COMPUTE
#undef ISSUE_TILE

    // epilogue: C[row, col], col = lane&15, row = (lane>>4)*4 + r  (m89 layout)
    const int ccol  = lane & 15;
    const int crow4 = (lane >> 4) * 4;
#pragma unroll
    for (int j = 0; j < 4; j++) {
        int col = n0 + wn*64 + j*16 + ccol;
        float bj = bias[col];
        if (MODE == 0) {
#pragma unroll
            for (int i = 0; i < IM; i++) {
#pragma unroll
                for (int r = 0; r < 4; r++) {
                    int row = m0 + wm*(TM/2) + i*16 + crow4 + r;
                    float v = acc[i][j][r] + bj;
                    v = v >= 0.f ? v : 0.01f * v;
                    Cout[(size_t)row * N + col] = (bf16_t)v;
                }
            }
        } else {
            int slot = rflag ? (511 - col) : (512 + col);
            int aj   = 511 - col;          // next step's xa = reverse(yb)
#pragma unroll
            for (int i = 0; i < IM; i++) {
#pragma unroll
                for (int r = 0; r < 4; r++) {
                    int row = m0 + wm*(TM/2) + i*16 + crow4 + r;
                    float t = acc[i][j][r] + bj;
                    float nv = S[(size_t)row * DD + slot] + rintf(t);
                    S[(size_t)row * DD + slot] = nv;
                    Abn[(size_t)row * D2 + aj] = (bf16_t)nv;
                }
            }
        }
    }
}

// ---- final discretized-logistic NLL reduction ----
__global__ __launch_bounds__(256)
void reduce_nll(const float* __restrict__ S, const float* __restrict__ mean,
                const float* __restrict__ log_scale, float* __restrict__ out)
{
    float local = 0.f;
    const int total = BQ * DD;
    for (int idx = blockIdx.x * blockDim.x + threadIdx.x; idx < total;
         idx += gridDim.x * blockDim.x) {
        int j = idx & (DD - 1);
        float z  = S[idx];
        float mu = mean[j];
        float sc = expf(log_scale[j]);
        float ua = (z + 0.5f - mu) / sc;
        float ub = (z - 0.5f - mu) / sc;
        float la = fminf(ua, 0.f) - log1pf(expf(-fabsf(ua)));
        float lb = fminf(ub, 0.f) - log1pf(expf(-fabsf(ub)));
        float lp = la + logf(1.0f - expf(lb - la) + 1e-8f);
        local += lp;
    }
    __shared__ float red[256];
    red[threadIdx.x] = local;
    __syncthreads();
    for (int s = 128; s > 0; s >>= 1) {
        if (threadIdx.x < s) red[threadIdx.x] += red[threadIdx.x + s];
        __syncthreads();
    }
    if (threadIdx.x == 0) atomicAdd(out, -red[0] * (1.0f / (float)BQ));
}

extern "C" void kernel_launch(void* const* d_in, const int* in_sizes, int n_in,
                              void* d_out, int out_size, void* d_ws, size_t ws_size,
                              hipStream_t stream)
{
    const float* x   = (const float*)d_in[0];
    const float* W1  = (const float*)d_in[1];
    const float* b1  = (const float*)d_in[2];
    const float* W2  = (const float*)d_in[3];
    const float* b2  = (const float*)d_in[4];
    const float* W3  = (const float*)d_in[5];
    const float* b3  = (const float*)d_in[6];
    const float* mean = (const float*)d_in[7];
    const float* lsc  = (const float*)d_in[8];

    char* ws = (char*)d_ws;
    bf16_t* Wt1 = (bf16_t*)ws; ws += (size_t)NF * NH * D2 * 2;   // 16 MB (NxK = 2048x512)
    bf16_t* Wt2 = (bf16_t*)ws; ws += (size_t)NF * NH * NH * 2;   // 64 MB
    bf16_t* Wt3 = (bf16_t*)ws; ws += (size_t)NF * D2 * NH * 2;   // 16 MB (512x2048)
    float*  S   = (float*)ws;  ws += (size_t)BQ * DD * 4;        // 32 MB
    bf16_t* Ab  = (bf16_t*)ws; ws += (size_t)BQ * D2 * 2;        //  8 MB
    bf16_t* H1  = (bf16_t*)ws; ws += (size_t)BQ * NH * 2;        // 32 MB
    bf16_t* H2  = (bf16_t*)ws;                                   // 32 MB  (total 200 MB)

    hipMemsetAsync(d_out, 0, sizeof(float), stream);

    dim3 blk(256);
    // W1: (K=512, N=2048) -> Wt1 (2048x512)
    transpose_bf16<<<dim3(NH/32, D2/32, NF), blk, 0, stream>>>(W1, Wt1, D2, NH);
    // W2: (2048, 2048)
    transpose_bf16<<<dim3(NH/32, NH/32, NF), blk, 0, stream>>>(W2, Wt2, NH, NH);
    // W3: (K=2048, N=512) -> Wt3 (512x2048)
    transpose_bf16<<<dim3(D2/32, NH/32, NF), blk, 0, stream>>>(W3, Wt3, NH, D2);

    copy_x<<<BQ * DD / 4 / 256, blk, 0, stream>>>((const float4*)x, (float4*)S);
    prep_A<<<BQ * D2 / 256, blk, 0, stream>>>(S, Ab);   // step 0 only

    for (int f = 0; f < NF; ++f) {
        int r = f & 1;
        // G1: (8192 x 512) @ (512 x 2048) -> H1
        gemm_kernel<0, D2, 128><<<dim3(NH/128, BQ/128), blk, 0, stream>>>(
            Ab, Wt1 + (size_t)f * NH * D2, b1 + (size_t)f * NH, H1, nullptr,
            nullptr, NH, 0);
        // G2: (8192 x 2048) @ (2048 x 2048) -> H2
        gemm_kernel<0, NH, 128><<<dim3(NH/128, BQ/128), blk, 0, stream>>>(
            H1, Wt2 + (size_t)f * NH * NH, b2 + (size_t)f * NH, H2, nullptr,
            nullptr, NH, 0);
        // G3: (8192 x 2048) @ (2048 x 512), TM=64 -> S update + next-A emit
        gemm_kernel<1, NH, 64><<<dim3(D2/128, BQ/64), blk, 0, stream>>>(
            H2, Wt3 + (size_t)f * D2 * NH, b3 + (size_t)f * D2, nullptr, S,
            Ab, D2, r);
    }

    reduce_nll<<<2048, blk, 0, stream>>>(S, mean, lsc, (float*)d_out);
}

// Round 6
// 1486.668 us; speedup vs baseline: 1.3029x; 1.0875x over previous
//
#include <hip/hip_runtime.h>
#include <hip/hip_bf16.h>
#include <cmath>

// ---------------------------------------------------------------------------
// IntegerDiscreteFlow on MI355X (gfx950)
// B=8192, D=1024, d2=512, N=2048, F=8 steps.
// State S (8192x1024 f32) updated in place; the [:, ::-1] reversal is an
// orientation bit (logical j <-> stored 1023-j), flipped each step.
// GEMMs in bf16 MFMA 16x16x32, fp32 accumulate.
// R2: XOR-swizzled LDS placement (bank conflicts -> 0).
// R3/R4: double-buffer -> BK=64; G3 emits next step's A (prep_A once).
// R5: ring-3 LDS pipeline, DMA issued before s_waitcnt vmcnt(NDMA) + raw
//     s_barrier (loads stay in flight across the barrier).
// R6: 128x256 block tile for G1/G2 (wave-tile 64x128, 32 MFMA per barrier
//     per wave — AITER-level amortization), 72 KB LDS, 2 blocks/CU (which is
//     all we were getting anyway). G3 stays 64x128.
// ---------------------------------------------------------------------------

typedef __bf16 bf16_t;
typedef bf16_t bf16x8 __attribute__((ext_vector_type(8)));
typedef float floatx4 __attribute__((ext_vector_type(4)));

#define BQ 8192
#define DD 1024
#define D2 512
#define NH 2048
#define NF 8

__device__ __forceinline__ void gload_lds16(const void* g, void* l) {
    __builtin_amdgcn_global_load_lds(
        (__attribute__((address_space(1))) void*)g,
        (__attribute__((address_space(3))) void*)l, 16, 0, 0);
}

// ---- weight convert+transpose: W (K x N f32, row-major) -> Wt (N x K bf16) --
__global__ __launch_bounds__(256)
void transpose_bf16(const float* __restrict__ W, bf16_t* __restrict__ Wt,
                    int K, int N) {
    __shared__ float tile[32][33];
    size_t fo = (size_t)blockIdx.z * K * N;
    int n0 = blockIdx.x * 32, k0 = blockIdx.y * 32;
    int tx = threadIdx.x & 31, ty = threadIdx.x >> 5;   // 32 x 8
    for (int i = 0; i < 4; i++)
        tile[ty + i*8][tx] = W[fo + (size_t)(k0 + ty + i*8) * N + n0 + tx];
    __syncthreads();
    for (int i = 0; i < 4; i++)
        Wt[fo + (size_t)(n0 + ty + i*8) * K + k0 + tx] = (bf16_t)tile[tx][ty + i*8];
}

// ---- copy x -> S (f32, vectorized) ----
__global__ __launch_bounds__(256)
void copy_x(const float4* __restrict__ x, float4* __restrict__ S) {
    int idx = blockIdx.x * blockDim.x + threadIdx.x;   // 2M threads
    S[idx] = x[idx];
}

// ---- build bf16 A operand (= logical xa) from S, identity orientation ----
__global__ __launch_bounds__(256)
void prep_A(const float* __restrict__ S, bf16_t* __restrict__ Ab) {
    int idx = blockIdx.x * blockDim.x + threadIdx.x;   // over 8192*512
    int m = idx >> 9;
    int j = idx & 511;
    Ab[idx] = (bf16_t)S[(size_t)m * DD + j];
}

// ---- GEMM: C = A(MxK bf16) @ B, B given transposed as Bt (NxK bf16) ----
// Block tile TM x TN, BK=32, ring-3 LDS pipeline, 4 waves (2x2), wave-tile
// (TM/2) x (TN/2).
// MODE 0: out = bf16( leaky_relu(acc + bias[n]) )
// MODE 1: S[m, slot(n)] += rint(acc + bias[n]); Abn[m, 511-n] = new value
template<int MODE, int K, int TM, int TN, int MINW>
__global__ __launch_bounds__(256, MINW)
void gemm_kernel(const bf16_t* __restrict__ A, const bf16_t* __restrict__ Bt,
                 const float* __restrict__ bias,
                 bf16_t* __restrict__ Cout, float* __restrict__ S,
                 bf16_t* __restrict__ Abn,
                 int N, int rflag)
{
    constexpr int IM   = TM / 32;          // i-fragments per wave
    constexpr int JN   = TN / 32;          // j-fragments per wave
    constexpr int NA   = TM / 64;          // A DMA instrs per tile
    constexpr int NBD  = TN / 64;          // B DMA instrs per tile
    constexpr int NDMA = NA + NBD;         // DMA instrs per tile
    constexpr int T    = K / 32;           // K-tiles
    static_assert((T - 1) % 3 == 0, "pipeline triple-unroll needs (T-1)%3==0");
    static_assert(JN % 4 == 0, "bff processed in groups of 4");

    __shared__ __align__(16) bf16_t As[3][TM * 32];
    __shared__ __align__(16) bf16_t Bs[3][TN * 32];

    const int tid  = threadIdx.x;
    const int lane = tid & 63;
    const int wave = tid >> 6;
    const int wm   = wave >> 1;            // 0..1
    const int wn   = wave & 1;             // 0..1
    const int m0   = blockIdx.y * TM;
    const int n0   = blockIdx.x * TN;

    // Staging map (per DMA instr u): thread t -> row u*64 + (t>>2), chunk
    // position p = t&3; global chunk fetched q = p ^ ((row>>1)&3) (XOR
    // swizzle; u*64 doesn't change (row>>1)&3). LDS dst = u*2048 + t*8 elems.
    const int srow = tid >> 2;
    const int sq   = ((tid & 3) ^ ((srow >> 1) & 3)) * 8;
    const bf16_t* agp = A  + (size_t)(m0 + srow) * K + sq;
    const bf16_t* bgp = Bt + (size_t)(n0 + srow) * K + sq;

    floatx4 acc[IM][JN];
#pragma unroll
    for (int i = 0; i < IM; i++)
#pragma unroll
        for (int j = 0; j < JN; j++)
            acc[i][j] = (floatx4){0.f, 0.f, 0.f, 0.f};

    // Fragment read: row rr = base + (lane&15) (base mult. of 16), chunk
    // c = lane>>4 stored at position c ^ ((rr>>1)&3) = c ^ ((lane>>1)&3).
    const int fr  = lane & 15;
    const int fp8 = ((lane >> 4) ^ ((lane >> 1) & 3)) * 8;

#define ISSUE_TILE(NB)                                                       \
    {                                                                        \
        _Pragma("unroll")                                                    \
        for (int u = 0; u < NA; u++)                                         \
            gload_lds16(agp + (size_t)(u*64) * K, &As[NB][u*2048 + tid*8]);  \
        _Pragma("unroll")                                                    \
        for (int u = 0; u < NBD; u++)                                        \
            gload_lds16(bgp + (size_t)(u*64) * K, &Bs[NB][u*2048 + tid*8]);  \
        agp += 32; bgp += 32;                                                \
    }

// bff processed in two groups of 4 to cap live registers at JN=8.
#define COMPUTE(CB)                                                          \
    {                                                                        \
        bf16x8 af[IM];                                                       \
        _Pragma("unroll")                                                    \
        for (int i = 0; i < IM; i++)                                         \
            af[i] = *(const bf16x8*)&As[CB][(wm*(TM/2) + i*16 + fr)*32 + fp8];\
        _Pragma("unroll")                                                    \
        for (int g2 = 0; g2 < JN/4; g2++) {                                  \
            bf16x8 bff[4];                                                   \
            _Pragma("unroll")                                                \
            for (int j = 0; j < 4; j++)                                      \
                bff[j] = *(const bf16x8*)                                    \
                    &Bs[CB][(wn*(TN/2) + (g2*4+j)*16 + fr)*32 + fp8];        \
            _Pragma("unroll")                                                \
            for (int i = 0; i < IM; i++)                                     \
                _Pragma("unroll")                                            \
                for (int j = 0; j < 4; j++)                                  \
                    acc[i][g2*4+j] = __builtin_amdgcn_mfma_f32_16x16x32_bf16(\
                                    af[i], bff[j], acc[i][g2*4+j], 0, 0, 0); \
        }                                                                    \
    }

#define PIPE_STEP(NB, CB)                                                    \
    {                                                                        \
        ISSUE_TILE(NB);                                                      \
        __builtin_amdgcn_s_waitcnt(0x0F70 | NDMA);  /* prev tile landed */   \
        __builtin_amdgcn_s_barrier();                                        \
        COMPUTE(CB);                                                         \
    }

    // prologue: tile 0 -> buf 0
    ISSUE_TILE(0);

    // steady state: tiles it = 3g+1, 3g+2, 3g+3 -> bufs 1, 2, 0
#pragma unroll 1
    for (int g = 0; g < (T - 1) / 3; ++g) {
        PIPE_STEP(1, 0);
        PIPE_STEP(2, 1);
        PIPE_STEP(0, 2);
    }
    // tail: compute tile T-1, which lives in buf (T-1)%3 == 0
    __builtin_amdgcn_s_waitcnt(0x0F70);            // vmcnt(0)
    __builtin_amdgcn_s_barrier();
    COMPUTE(0);

#undef PIPE_STEP
#undef COMPUTE
#undef ISSUE_TILE

    // epilogue: C[row, col], col = lane&15, row = (lane>>4)*4 + r  (m89 layout)
    const int ccol  = lane & 15;
    const int crow4 = (lane >> 4) * 4;
#pragma unroll
    for (int j = 0; j < JN; j++) {
        int col = n0 + wn*(TN/2) + j*16 + ccol;
        float bj = bias[col];
        if (MODE == 0) {
#pragma unroll
            for (int i = 0; i < IM; i++) {
#pragma unroll
                for (int r = 0; r < 4; r++) {
                    int row = m0 + wm*(TM/2) + i*16 + crow4 + r;
                    float v = acc[i][j][r] + bj;
                    v = v >= 0.f ? v : 0.01f * v;
                    Cout[(size_t)row * N + col] = (bf16_t)v;
                }
            }
        } else {
            int slot = rflag ? (511 - col) : (512 + col);
            int aj   = 511 - col;          // next step's xa = reverse(yb)
#pragma unroll
            for (int i = 0; i < IM; i++) {
#pragma unroll
                for (int r = 0; r < 4; r++) {
                    int row = m0 + wm*(TM/2) + i*16 + crow4 + r;
                    float t = acc[i][j][r] + bj;
                    float nv = S[(size_t)row * DD + slot] + rintf(t);
                    S[(size_t)row * DD + slot] = nv;
                    Abn[(size_t)row * D2 + aj] = (bf16_t)nv;
                }
            }
        }
    }
}

// ---- final discretized-logistic NLL reduction ----
__global__ __launch_bounds__(256)
void reduce_nll(const float* __restrict__ S, const float* __restrict__ mean,
                const float* __restrict__ log_scale, float* __restrict__ out)
{
    float local = 0.f;
    const int total = BQ * DD;
    for (int idx = blockIdx.x * blockDim.x + threadIdx.x; idx < total;
         idx += gridDim.x * blockDim.x) {
        int j = idx & (DD - 1);
        float z  = S[idx];
        float mu = mean[j];
        float sc = expf(log_scale[j]);
        float ua = (z + 0.5f - mu) / sc;
        float ub = (z - 0.5f - mu) / sc;
        float la = fminf(ua, 0.f) - log1pf(expf(-fabsf(ua)));
        float lb = fminf(ub, 0.f) - log1pf(expf(-fabsf(ub)));
        float lp = la + logf(1.0f - expf(lb - la) + 1e-8f);
        local += lp;
    }
    __shared__ float red[256];
    red[threadIdx.x] = local;
    __syncthreads();
    for (int s = 128; s > 0; s >>= 1) {
        if (threadIdx.x < s) red[threadIdx.x] += red[threadIdx.x + s];
        __syncthreads();
    }
    if (threadIdx.x == 0) atomicAdd(out, -red[0] * (1.0f / (float)BQ));
}

extern "C" void kernel_launch(void* const* d_in, const int* in_sizes, int n_in,
                              void* d_out, int out_size, void* d_ws, size_t ws_size,
                              hipStream_t stream)
{
    const float* x   = (const float*)d_in[0];
    const float* W1  = (const float*)d_in[1];
    const float* b1  = (const float*)d_in[2];
    const float* W2  = (const float*)d_in[3];
    const float* b2  = (const float*)d_in[4];
    const float* W3  = (const float*)d_in[5];
    const float* b3  = (const float*)d_in[6];
    const float* mean = (const float*)d_in[7];
    const float* lsc  = (const float*)d_in[8];

    char* ws = (char*)d_ws;
    bf16_t* Wt1 = (bf16_t*)ws; ws += (size_t)NF * NH * D2 * 2;   // 16 MB (NxK = 2048x512)
    bf16_t* Wt2 = (bf16_t*)ws; ws += (size_t)NF * NH * NH * 2;   // 64 MB
    bf16_t* Wt3 = (bf16_t*)ws; ws += (size_t)NF * D2 * NH * 2;   // 16 MB (512x2048)
    float*  S   = (float*)ws;  ws += (size_t)BQ * DD * 4;        // 32 MB
    bf16_t* Ab  = (bf16_t*)ws; ws += (size_t)BQ * D2 * 2;        //  8 MB
    bf16_t* H1  = (bf16_t*)ws; ws += (size_t)BQ * NH * 2;        // 32 MB
    bf16_t* H2  = (bf16_t*)ws;                                   // 32 MB  (total 200 MB)

    hipMemsetAsync(d_out, 0, sizeof(float), stream);

    dim3 blk(256);
    // W1: (K=512, N=2048) -> Wt1 (2048x512)
    transpose_bf16<<<dim3(NH/32, D2/32, NF), blk, 0, stream>>>(W1, Wt1, D2, NH);
    // W2: (2048, 2048)
    transpose_bf16<<<dim3(NH/32, NH/32, NF), blk, 0, stream>>>(W2, Wt2, NH, NH);
    // W3: (K=2048, N=512) -> Wt3 (512x2048)
    transpose_bf16<<<dim3(D2/32, NH/32, NF), blk, 0, stream>>>(W3, Wt3, NH, D2);

    copy_x<<<BQ * DD / 4 / 256, blk, 0, stream>>>((const float4*)x, (float4*)S);
    prep_A<<<BQ * D2 / 256, blk, 0, stream>>>(S, Ab);   // step 0 only

    for (int f = 0; f < NF; ++f) {
        int r = f & 1;
        // G1: (8192 x 512) @ (512 x 2048) -> H1   [128x256 tiles, 512 blocks]
        gemm_kernel<0, D2, 128, 256, 2><<<dim3(NH/256, BQ/128), blk, 0, stream>>>(
            Ab, Wt1 + (size_t)f * NH * D2, b1 + (size_t)f * NH, H1, nullptr,
            nullptr, NH, 0);
        // G2: (8192 x 2048) @ (2048 x 2048) -> H2 [128x256 tiles, 512 blocks]
        gemm_kernel<0, NH, 128, 256, 2><<<dim3(NH/256, BQ/128), blk, 0, stream>>>(
            H1, Wt2 + (size_t)f * NH * NH, b2 + (size_t)f * NH, H2, nullptr,
            nullptr, NH, 0);
        // G3: (8192 x 2048) @ (2048 x 512), 64x128 tiles -> S + next-A emit
        gemm_kernel<1, NH, 64, 128, 3><<<dim3(D2/128, BQ/64), blk, 0, stream>>>(
            H2, Wt3 + (size_t)f * D2 * NH, b3 + (size_t)f * D2, nullptr, S,
            Ab, D2, r);
    }

    reduce_nll<<<2048, blk, 0, stream>>>(S, mean, lsc, (float*)d_out);
}